// Round 2
// baseline (111.916 us; speedup 1.0000x reference)
//
#include <hip/hip_runtime.h>
#include <hip/hip_bf16.h>

// PositionalEmbedding: out[b,t,:] = tok_weight[x[b,t],:] + pos_weight[t,:]
// B=4, T=4096, E=512, fp32. Pure memory-bound gather+add.
//
// R2 layout: one wave per (b,t) row.
//   - row index is wave-uniform -> x[row] compiles to a scalar load
//   - each lane handles float4 #lane and #(lane+64) of the 128-float4 row:
//     two fully-coalesced 1 KiB segments per wave per stream
//   - nontemporal stores on out (no reuse) to keep tok/pos rows resident
//     in L2/L3 for the ~22% duplicate token rows.

#define TT 4096      // TIME / sequence length
#define EV4 128      // float4 per row (E=512)

typedef float f32x4 __attribute__((ext_vector_type(4)));

__global__ __launch_bounds__(256) void pos_embed_kernel(
    const int* __restrict__ x,            // [B*T]
    const float4* __restrict__ tok_w,     // [VOCAB, EV4]
    const float4* __restrict__ pos_w,     // [TT, EV4]
    float4* __restrict__ out,             // [B*T, EV4]
    int nrows)                            // B*T = 16384
{
    const int lane = threadIdx.x & 63;
    const int wave = threadIdx.x >> 6;            // 4 waves/block
    const int row  = blockIdx.x * 4 + wave;
    if (row >= nrows) return;

    const int t = row & (TT - 1);
    // row is wave-uniform; force the scalar path explicitly
    const int tok_row = __builtin_amdgcn_readfirstlane(x[row]);

    const float4* ta = tok_w + (size_t)tok_row * EV4;
    const float4* pa = pos_w + (size_t)t * EV4;
    float4*       oa = out   + (size_t)row * EV4;

    float4 a0 = ta[lane];
    float4 a1 = ta[lane + 64];
    float4 p0 = pa[lane];
    float4 p1 = pa[lane + 64];

    f32x4 r0 = {a0.x + p0.x, a0.y + p0.y, a0.z + p0.z, a0.w + p0.w};
    f32x4 r1 = {a1.x + p1.x, a1.y + p1.y, a1.z + p1.z, a1.w + p1.w};

    __builtin_nontemporal_store(r0, (f32x4*)&oa[lane]);
    __builtin_nontemporal_store(r1, (f32x4*)&oa[lane + 64]);
}

extern "C" void kernel_launch(void* const* d_in, const int* in_sizes, int n_in,
                              void* d_out, int out_size, void* d_ws, size_t ws_size,
                              hipStream_t stream) {
    const int*    x     = (const int*)d_in[0];      // [B,T] int32
    const float4* tok_w = (const float4*)d_in[1];   // [VOCAB, E] fp32
    const float4* pos_w = (const float4*)d_in[2];   // [T, E] fp32
    float4*       out   = (float4*)d_out;           // [B,T,E] fp32

    int nrows = out_size / 512;                     // 16384 rows
    int block = 256;                                // 4 waves = 4 rows/block
    int grid  = nrows / 4;                          // 4096 blocks

    pos_embed_kernel<<<grid, block, 0, stream>>>(x, tok_w, pos_w, out, nrows);
}